// Round 1
// baseline (394.313 us; speedup 1.0000x reference)
//
#include <hip/hip_runtime.h>
#include <stdint.h>

typedef __bf16 bf16;
typedef __bf16 bf16x8 __attribute__((ext_vector_type(8)));
typedef float  f32x4  __attribute__((ext_vector_type(4)));
typedef uint32_t u32;
typedef uint64_t u64;

#define SCALE_L2E 0.18033688011112042f   // (1/8) * log2(e)

__device__ __forceinline__ void gld_lds16(const void* gsrc, void* ldst) {
  __builtin_amdgcn_global_load_lds(
      (const __attribute__((address_space(1))) void*)gsrc,
      (__attribute__((address_space(3))) void*)ldst, 16, 0, 0);
}

// ---------------- stage 1: conversions / packing ----------------

__global__ void cvt_f32_bf16(const float* __restrict__ in, bf16* __restrict__ out, int n8) {
  int stride = gridDim.x * blockDim.x;
  for (int i = blockIdx.x * blockDim.x + threadIdx.x; i < n8; i += stride) {
    const float4* p = (const float4*)(in + (size_t)i * 8);
    float4 a = p[0], b = p[1];
    bf16x8 v;
    v[0]=(bf16)a.x; v[1]=(bf16)a.y; v[2]=(bf16)a.z; v[3]=(bf16)a.w;
    v[4]=(bf16)b.x; v[5]=(bf16)b.y; v[6]=(bf16)b.z; v[7]=(bf16)b.w;
    *(bf16x8*)(out + (size_t)i * 8) = v;
  }
}

// Wt layout: 4 matrices [1024][1024], row n contiguous over k.
// s<3: Wt[s][n][k] = Ws[h=n>>6][m=k][d=n&63];  s==3: Wt[3][n][k] = Wo[n][k]
__global__ void pack_w(const float* __restrict__ Wq, const float* __restrict__ Wk,
                       const float* __restrict__ Wv, const float* __restrict__ Wo,
                       bf16* __restrict__ Wt) {
  int s = blockIdx.z;
  int tid = blockIdx.x * blockDim.x + threadIdx.x;   // 0..131071
  int n = tid >> 7, kb = tid & 127;
  const float* W = (s == 0) ? Wq : (s == 1) ? Wk : (s == 2) ? Wv : Wo;
  bf16x8 v;
  if (s < 3) {
#pragma unroll
    for (int j = 0; j < 8; ++j)
      v[j] = (bf16)W[((n >> 6) << 16) + (kb * 8 + j) * 64 + (n & 63)];
  } else {
    const float4* p = (const float4*)&W[n * 1024 + kb * 8];
    float4 a = p[0], b = p[1];
    v[0]=(bf16)a.x; v[1]=(bf16)a.y; v[2]=(bf16)a.z; v[3]=(bf16)a.w;
    v[4]=(bf16)b.x; v[5]=(bf16)b.y; v[6]=(bf16)b.z; v[7]=(bf16)b.w;
  }
  *(bf16x8*)&Wt[(size_t)s * 1048576 + (size_t)n * 1024 + kb * 8] = v;
}

// mask int32 -> bitmask, bit (b,l,key) at mbits[(b*2048+l)*64 + key/32], bit key&31
__global__ void pack_mask(const int* __restrict__ mask, u32* __restrict__ mbits, int total) {
  int stride = gridDim.x * blockDim.x;
  for (int idx = blockIdx.x * blockDim.x + threadIdx.x; idx < total; idx += stride) {
    int v = mask[idx];
    u64 bal = __ballot(v != 0);
    if ((threadIdx.x & 63) == 0)
      *(u64*)&mbits[idx >> 5] = bal;      // idx multiple of 64 here -> 8B aligned
  }
}

// ---------------- stage 2: m97-style bf16 GEMM, C = A(row,k) . Bt(col,k)^T ----------------
// K fixed 1024, both strides 1024. Tiles 128x128, BK=32, 4 waves (2x2 of 64x64).
// EPI 0: write bf16 at [(b*16+h)*2048+l]*64+d  (row=b*2048+l over M=8192, col=h*64+d over N=1024)
// EPI 1: write bf16 at [(bz*1024+row)*2048+col] (Vt, M=1024 rows=hd, N=2048 cols=l)
// EPI 2: write f32 d_out[row*1024+col] + bias[col]
template<int EPI>
__global__ __launch_bounds__(256, 2)
void gemm_bt(const bf16* __restrict__ A, const bf16* __restrict__ Bt,
             void* __restrict__ Cout, const float* __restrict__ bias,
             size_t a_bstride, size_t b_bstride) {
  const int gx = gridDim.x;
  int lin = blockIdx.y * gx + blockIdx.x;
  int nwg = gx * gridDim.y;
  int swz = (lin & 7) * (nwg >> 3) + (lin >> 3);   // XCD-contiguous chunks (nwg % 8 == 0)
  int bx = swz % gx, by = swz / gx;
  const int bz = blockIdx.z;
  A  += a_bstride * bz;
  Bt += b_bstride * bz;
  const int row0 = by * 128, col0 = bx * 128;

  __shared__ bf16 sA[128 * 32];
  __shared__ bf16 sB[128 * 32];

  const int lane = threadIdx.x & 63, w = threadIdx.x >> 6;
  const int c = lane & 15, g = lane >> 4;
  const int wr = w >> 1, wc = w & 1;

  f32x4 acc[4][4] = {};

  const bf16* Ap = A + (size_t)row0 * 1024;
  const bf16* Bp = Bt + (size_t)col0 * 1024;

  for (int k0 = 0; k0 < 1024; k0 += 32) {
    __syncthreads();
#pragma unroll
    for (int i = 0; i < 2; ++i) {
      int u = (w * 2 + i) * 64 + lane;        // 0..511 ; row=u>>2, 16B part=u&3
      int r = u >> 2, part = u & 3;
      gld_lds16(Ap + (size_t)r * 1024 + k0 + part * 8, (char*)sA + (size_t)(w * 2 + i) * 1024);
      gld_lds16(Bp + (size_t)r * 1024 + k0 + part * 8, (char*)sB + (size_t)(w * 2 + i) * 1024);
    }
    __syncthreads();

    bf16x8 af[4], bfr[4];
#pragma unroll
    for (int m = 0; m < 4; ++m)
      af[m] = *(const bf16x8*)&sA[(wr * 64 + m * 16 + c) * 32 + g * 8];
#pragma unroll
    for (int n = 0; n < 4; ++n)
      bfr[n] = *(const bf16x8*)&sB[(wc * 64 + n * 16 + c) * 32 + g * 8];
#pragma unroll
    for (int m = 0; m < 4; ++m)
#pragma unroll
      for (int n = 0; n < 4; ++n)
        acc[m][n] = __builtin_amdgcn_mfma_f32_16x16x32_bf16(af[m], bfr[n], acc[m][n], 0, 0, 0);
  }

#pragma unroll
  for (int m = 0; m < 4; ++m) {
    int row_base = row0 + wr * 64 + m * 16 + g * 4;
#pragma unroll
    for (int n = 0; n < 4; ++n) {
      int col = col0 + wc * 64 + n * 16 + c;
#pragma unroll
      for (int r = 0; r < 4; ++r) {
        int row = row_base + r;
        float val = acc[m][n][r];
        if (EPI == 0) {
          int b = row >> 11, l = row & 2047, h = col >> 6, d = col & 63;
          ((bf16*)Cout)[(((size_t)(b * 16 + h) * 2048 + l) << 6) + d] = (bf16)val;
        } else if (EPI == 1) {
          ((bf16*)Cout)[((size_t)(bz * 1024 + row)) * 2048 + col] = (bf16)val;
        } else {
          ((float*)Cout)[(size_t)row * 1024 + col] = val + bias[col];
        }
      }
    }
  }
}

// ---------------- stage 3: flash attention ----------------
// grid (16 q-tiles, 64 bh). 4 waves x 32 q-rows. KV tiles of 64.
// Swapped QK^T: St[key][q] = mfma(K_frag, Q_frag). Softmax per q = in-lane 16 + shfl 16/32.
// PV as O^T[d][q] = mfma(Vt_frag, P_frag) with P via wave-private swizzled LDS.
__global__ __launch_bounds__(256, 2)
void attn_fwd(const bf16* __restrict__ Qp, const bf16* __restrict__ Kp,
              const bf16* __restrict__ Vt, const u32* __restrict__ mbits,
              bf16* __restrict__ X) {
  int lin = blockIdx.y * 16 + blockIdx.x;          // 1024 wgs
  int swz = (lin & 7) * 128 + (lin >> 3);          // XCD swizzle: 8 bh per XCD chunk
  int qt = swz & 15, bh = swz >> 4;
  int b = bh >> 4, h = bh & 15;
  int q0 = qt * 128;

  const int lane = threadIdx.x & 63, w = threadIdx.x >> 6;
  const int c = lane & 15, g = lane >> 4;

  __shared__ char smem[32768];
  bf16* sK = (bf16*)smem;                  // [64 keys][64 d], 16B-block XOR swizzled
  bf16* sV = (bf16*)(smem + 8192);         // [64 d][64 keys], swizzled
  char* sPw = smem + 16384 + w * 4096;     // per-wave P: [32 q][64 keys] bf16, swizzled

  const bf16* Qbase = Qp + ((size_t)bh * 2048) * 64;
  const bf16* Kbase = Kp + ((size_t)bh * 2048) * 64;
  const bf16* Vbase = Vt + ((size_t)(b * 1024 + h * 64)) * 2048;
  const u32*  Mbase = mbits + (size_t)(b * 2048) * 64;

  // Q fragments in registers (reused across all KV tiles)
  bf16x8 qf[2][2];
#pragma unroll
  for (int nq = 0; nq < 2; ++nq) {
    int qg = q0 + w * 32 + nq * 16 + c;
#pragma unroll
    for (int kk = 0; kk < 2; ++kk)
      qf[nq][kk] = *(const bf16x8*)&Qbase[(size_t)qg * 64 + kk * 32 + g * 8];
  }

  f32x4 oacc[4][2] = {};                  // [md][nq] : O^T[d][q]
  float mrun[2] = {-1e30f, -1e30f};
  float lrun[2] = {0.f, 0.f};

  for (int k0 = 0; k0 < 2048; k0 += 64) {
    __syncthreads();
    // stage K tile and Vt tile (reg -> swizzled LDS)
#pragma unroll
    for (int i = 0; i < 2; ++i) {
      int u = i * 256 + threadIdx.x;       // 0..511 ; row=u>>3, blk=u&7
      int row = u >> 3, blk = u & 7;
      uint4 kv = *(const uint4*)&Kbase[(size_t)(k0 + row) * 64 + blk * 8];
      *(uint4*)((char*)sK + row * 128 + ((blk ^ (row & 7)) * 16)) = kv;
      uint4 vv = *(const uint4*)&Vbase[(size_t)row * 2048 + k0 + blk * 8];
      *(uint4*)((char*)sV + row * 128 + ((blk ^ (row & 7)) * 16)) = vv;
    }
    __syncthreads();

    // QK^T (swapped): St[key][q]
    f32x4 st[4][2] = {};
#pragma unroll
    for (int kk = 0; kk < 2; ++kk) {
#pragma unroll
      for (int nk = 0; nk < 4; ++nk) {
        int row = nk * 16 + c;            // key local
        bf16x8 kf = *(const bf16x8*)((const char*)sK + row * 128 + (((kk * 4 + g) ^ (row & 7)) * 16));
#pragma unroll
        for (int nq = 0; nq < 2; ++nq)
          st[nk][nq] = __builtin_amdgcn_mfma_f32_16x16x32_bf16(kf, qf[nq][kk], st[nk][nq], 0, 0, 0);
      }
    }

    // mask + online softmax + P -> LDS (bf16)
#pragma unroll
    for (int nq = 0; nq < 2; ++nq) {
      int qg = q0 + w * 32 + nq * 16 + c;
      u64 mw = *(const u64*)&Mbase[(size_t)qg * 64 + (k0 >> 5)];
      float p[16];
      float tmax = -1e30f;
#pragma unroll
      for (int nk = 0; nk < 4; ++nk)
#pragma unroll
        for (int r = 0; r < 4; ++r) {
          int kl = nk * 16 + g * 4 + r;
          float s = ((mw >> kl) & 1) ? st[nk][nq][r] * SCALE_L2E : -1e30f;
          p[nk * 4 + r] = s;
          tmax = fmaxf(tmax, s);
        }
      tmax = fmaxf(tmax, __shfl_xor(tmax, 16));
      tmax = fmaxf(tmax, __shfl_xor(tmax, 32));
      float mnew = fmaxf(mrun[nq], tmax);
      float alpha = __builtin_exp2f(mrun[nq] - mnew);
      mrun[nq] = mnew;
      float lsum = 0.f;
#pragma unroll
      for (int i = 0; i < 16; ++i) {
        float e = __builtin_exp2f(p[i] - mnew);
        p[i] = e;
        lsum += e;
      }
      lsum += __shfl_xor(lsum, 16);
      lsum += __shfl_xor(lsum, 32);
      lrun[nq] = lrun[nq] * alpha + lsum;
#pragma unroll
      for (int md = 0; md < 4; ++md)
#pragma unroll
        for (int r = 0; r < 4; ++r)
          oacc[md][nq][r] *= alpha;

      int ql = nq * 16 + c;               // wave-local q row 0..31
#pragma unroll
      for (int nk = 0; nk < 4; ++nk)
#pragma unroll
        for (int t = 0; t < 2; ++t) {
          union { bf16 hh[2]; u32 ww; } uu;
          uu.hh[0] = (bf16)p[nk * 4 + t * 2];
          uu.hh[1] = (bf16)p[nk * 4 + t * 2 + 1];
          int key0 = nk * 16 + g * 4 + t * 2;
          int blk = key0 >> 3, off = key0 & 7;
          *(u32*)(sPw + ql * 128 + ((blk ^ (ql & 7)) * 16) + off * 2) = uu.ww;
        }
    }

    // PV: O^T[d][q] += Vt . P^T
#pragma unroll
    for (int kk = 0; kk < 2; ++kk) {
      bf16x8 pf[2];
#pragma unroll
      for (int nq = 0; nq < 2; ++nq) {
        int ql = nq * 16 + c;
        pf[nq] = *(const bf16x8*)(sPw + ql * 128 + (((kk * 4 + g) ^ (ql & 7)) * 16));
      }
#pragma unroll
      for (int md = 0; md < 4; ++md) {
        int row = md * 16 + c;            // d local
        bf16x8 vf = *(const bf16x8*)((const char*)sV + row * 128 + (((kk * 4 + g) ^ (row & 7)) * 16));
#pragma unroll
        for (int nq = 0; nq < 2; ++nq)
          oacc[md][nq] = __builtin_amdgcn_mfma_f32_16x16x32_bf16(vf, pf[nq], oacc[md][nq], 0, 0, 0);
      }
    }
  }

  // epilogue: O^T -> LDS transpose -> coalesced bf16 write to X[b*2048+q][h*64+d]
  __syncthreads();
  char* Xl = smem;                         // 16KB: [128 q][64 d] bf16, swizzled
#pragma unroll
  for (int nq = 0; nq < 2; ++nq) {
    float inv = 1.f / lrun[nq];
    int ql = w * 32 + nq * 16 + c;         // block-local q row
#pragma unroll
    for (int md = 0; md < 4; ++md)
#pragma unroll
      for (int r = 0; r < 4; ++r) {
        int d = md * 16 + g * 4 + r;
        int blk = d >> 3, off = d & 7;
        *(bf16*)(Xl + ql * 128 + ((blk ^ (ql & 7)) * 16) + off * 2) = (bf16)(oacc[md][nq][r] * inv);
      }
  }
  __syncthreads();
#pragma unroll
  for (int i = 0; i < 4; ++i) {
    int u = i * 256 + threadIdx.x;         // 0..1023 : row=u>>3, blk=u&7
    int row = u >> 3, blk = u & 7;
    uint4 xv = *(const uint4*)(Xl + row * 128 + ((blk ^ (row & 7)) * 16));
    *(uint4*)&X[(size_t)(b * 2048 + q0 + row) * 1024 + h * 64 + blk * 8] = xv;
  }
}

// ---------------- launch ----------------

extern "C" void kernel_launch(void* const* d_in, const int* in_sizes, int n_in,
                              void* d_out, int out_size, void* d_ws, size_t ws_size,
                              hipStream_t stream) {
  const float* q    = (const float*)d_in[0];
  const float* k    = (const float*)d_in[1];
  const float* v    = (const float*)d_in[2];
  const int*   mask = (const int*)d_in[3];
  const float* Wq   = (const float*)d_in[4];
  const float* Wk   = (const float*)d_in[5];
  const float* Wv   = (const float*)d_in[6];
  const float* Wo   = (const float*)d_in[7];
  const float* Wb   = (const float*)d_in[8];

  char* ws = (char*)d_ws;
  bf16* qb = (bf16*)(ws + 0);             // 16 MB each
  bf16* kb = (bf16*)(ws + 16777216);
  bf16* vb = (bf16*)(ws + 33554432);
  bf16* Wt = (bf16*)(ws + 50331648);      // 8 MB (4 packed 1024x1024)
  bf16* Qp = (bf16*)(ws + 58720256);
  bf16* Kp = (bf16*)(ws + 75497472);
  bf16* Vt = (bf16*)(ws + 92274688);
  bf16* Xb = (bf16*)(ws + 109051904);
  u32*  mb = (u32*) (ws + 125829120);     // 2 MB bitmask

  cvt_f32_bf16<<<1024, 256, 0, stream>>>(q, qb, 1048576);
  cvt_f32_bf16<<<1024, 256, 0, stream>>>(k, kb, 1048576);
  cvt_f32_bf16<<<1024, 256, 0, stream>>>(v, vb, 1048576);
  pack_w<<<dim3(512, 1, 4), 256, 0, stream>>>(Wq, Wk, Wv, Wo, Wt);
  pack_mask<<<2048, 256, 0, stream>>>(mask, mb, 16777216);

  // Q = q.Wq, K = k.Wk  -> [bh][l][d]
  gemm_bt<0><<<dim3(8, 64, 1), 256, 0, stream>>>(qb, Wt,            Qp, nullptr, 0, 0);
  gemm_bt<0><<<dim3(8, 64, 1), 256, 0, stream>>>(kb, Wt + 1048576,  Kp, nullptr, 0, 0);
  // Vt[b][hd][l] = Wv^T . v^T  per batch
  gemm_bt<1><<<dim3(16, 8, 4), 256, 0, stream>>>(Wt + 2097152, vb,  Vt, nullptr, 0, 2097152);

  attn_fwd<<<dim3(16, 64, 1), 256, 0, stream>>>(Qp, Kp, Vt, mb, Xb);

  // out = X . Wo^T + b  (f32 out)
  gemm_bt<2><<<dim3(8, 64, 1), 256, 0, stream>>>(Xb, Wt + 3145728, (float*)d_out, Wb, 0, 0);
}

// Round 2
// 289.201 us; speedup vs baseline: 1.3635x; 1.3635x over previous
//
#include <hip/hip_runtime.h>
#include <stdint.h>

typedef __bf16 bf16;
typedef __bf16 bf16x8 __attribute__((ext_vector_type(8)));
typedef float  f32x4  __attribute__((ext_vector_type(4)));
typedef uint32_t u32;
typedef uint64_t u64;

#define SCALE_L2E 0.18033688011112042f   // (1/8) * log2(e)

__device__ __forceinline__ void gld_lds16(const void* gsrc, void* ldst) {
  __builtin_amdgcn_global_load_lds(
      (const __attribute__((address_space(1))) void*)gsrc,
      (__attribute__((address_space(3))) void*)ldst, 16, 0, 0);
}

// ---------------- stage 1: conversions / packing ----------------

__global__ void cvt_f32_bf16(const float* __restrict__ in, bf16* __restrict__ out, int n8) {
  int stride = gridDim.x * blockDim.x;
  for (int i = blockIdx.x * blockDim.x + threadIdx.x; i < n8; i += stride) {
    const float4* p = (const float4*)(in + (size_t)i * 8);
    float4 a = p[0], b = p[1];
    bf16x8 v;
    v[0]=(bf16)a.x; v[1]=(bf16)a.y; v[2]=(bf16)a.z; v[3]=(bf16)a.w;
    v[4]=(bf16)b.x; v[5]=(bf16)b.y; v[6]=(bf16)b.z; v[7]=(bf16)b.w;
    *(bf16x8*)(out + (size_t)i * 8) = v;
  }
}

// Wt layout: 4 matrices [1024][1024], row n contiguous over k.
// s<3: Wt[s][n][k] = Ws[h=n>>6][m=k][d=n&63];  s==3: Wt[3][n][k] = Wo[n][k]
__global__ void pack_w(const float* __restrict__ Wq, const float* __restrict__ Wk,
                       const float* __restrict__ Wv, const float* __restrict__ Wo,
                       bf16* __restrict__ Wt) {
  int s = blockIdx.z;
  int tid = blockIdx.x * blockDim.x + threadIdx.x;   // 0..131071
  int n = tid >> 7, kb = tid & 127;
  const float* W = (s == 0) ? Wq : (s == 1) ? Wk : (s == 2) ? Wv : Wo;
  bf16x8 v;
  if (s < 3) {
#pragma unroll
    for (int j = 0; j < 8; ++j)
      v[j] = (bf16)W[((n >> 6) << 16) + (kb * 8 + j) * 64 + (n & 63)];
  } else {
    const float4* p = (const float4*)&W[n * 1024 + kb * 8];
    float4 a = p[0], b = p[1];
    v[0]=(bf16)a.x; v[1]=(bf16)a.y; v[2]=(bf16)a.z; v[3]=(bf16)a.w;
    v[4]=(bf16)b.x; v[5]=(bf16)b.y; v[6]=(bf16)b.z; v[7]=(bf16)b.w;
  }
  *(bf16x8*)&Wt[(size_t)s * 1048576 + (size_t)n * 1024 + kb * 8] = v;
}

// mask int32 -> bitmask, bit (b,l,key) at mbits[(b*2048+l)*64 + key/32], bit key&31
__global__ void pack_mask(const int* __restrict__ mask, u32* __restrict__ mbits, int total) {
  int stride = gridDim.x * blockDim.x;
  for (int idx = blockIdx.x * blockDim.x + threadIdx.x; idx < total; idx += stride) {
    int v = mask[idx];
    u64 bal = __ballot(v != 0);
    if ((threadIdx.x & 63) == 0)
      *(u64*)&mbits[idx >> 5] = bal;      // idx multiple of 64 here -> 8B aligned
  }
}

// ---------------- stage 2: m97-style bf16 GEMM, C = A(row,k) . Bt(col,k)^T ----------------
template<int EPI>
__global__ __launch_bounds__(256, 2)
void gemm_bt(const bf16* __restrict__ A, const bf16* __restrict__ Bt,
             void* __restrict__ Cout, const float* __restrict__ bias,
             size_t a_bstride, size_t b_bstride, float cscale) {
  const int gx = gridDim.x;
  int lin = blockIdx.y * gx + blockIdx.x;
  int nwg = gx * gridDim.y;
  int swz = (lin & 7) * (nwg >> 3) + (lin >> 3);   // XCD-contiguous chunks (nwg % 8 == 0)
  int bx = swz % gx, by = swz / gx;
  const int bz = blockIdx.z;
  A  += a_bstride * bz;
  Bt += b_bstride * bz;
  const int row0 = by * 128, col0 = bx * 128;

  __shared__ bf16 sA[128 * 32];
  __shared__ bf16 sB[128 * 32];

  const int lane = threadIdx.x & 63, w = threadIdx.x >> 6;
  const int c = lane & 15, g = lane >> 4;
  const int wr = w >> 1, wc = w & 1;

  f32x4 acc[4][4] = {};

  const bf16* Ap = A + (size_t)row0 * 1024;
  const bf16* Bp = Bt + (size_t)col0 * 1024;

  for (int k0 = 0; k0 < 1024; k0 += 32) {
    __syncthreads();
#pragma unroll
    for (int i = 0; i < 2; ++i) {
      int u = (w * 2 + i) * 64 + lane;        // 0..511 ; row=u>>2, 16B part=u&3
      int r = u >> 2, part = u & 3;
      gld_lds16(Ap + (size_t)r * 1024 + k0 + part * 8, (char*)sA + (size_t)(w * 2 + i) * 1024);
      gld_lds16(Bp + (size_t)r * 1024 + k0 + part * 8, (char*)sB + (size_t)(w * 2 + i) * 1024);
    }
    __syncthreads();

    bf16x8 af[4], bfr[4];
#pragma unroll
    for (int m = 0; m < 4; ++m)
      af[m] = *(const bf16x8*)&sA[(wr * 64 + m * 16 + c) * 32 + g * 8];
#pragma unroll
    for (int n = 0; n < 4; ++n)
      bfr[n] = *(const bf16x8*)&sB[(wc * 64 + n * 16 + c) * 32 + g * 8];
#pragma unroll
    for (int m = 0; m < 4; ++m)
#pragma unroll
      for (int n = 0; n < 4; ++n)
        acc[m][n] = __builtin_amdgcn_mfma_f32_16x16x32_bf16(af[m], bfr[n], acc[m][n], 0, 0, 0);
  }

#pragma unroll
  for (int m = 0; m < 4; ++m) {
    int row_base = row0 + wr * 64 + m * 16 + g * 4;
#pragma unroll
    for (int n = 0; n < 4; ++n) {
      int col = col0 + wc * 64 + n * 16 + c;
#pragma unroll
      for (int r = 0; r < 4; ++r) {
        int row = row_base + r;
        float val = acc[m][n][r];
        if (EPI == 0) {
          int b = row >> 11, l = row & 2047, h = col >> 6, d = col & 63;
          ((bf16*)Cout)[(((size_t)(b * 16 + h) * 2048 + l) << 6) + d] = (bf16)(val * cscale);
        } else if (EPI == 1) {
          ((bf16*)Cout)[((size_t)(bz * 1024 + row)) * 2048 + col] = (bf16)val;
        } else {
          ((float*)Cout)[(size_t)row * 1024 + col] = val + bias[col];
        }
      }
    }
  }
}

// ---------------- stage 3: flash attention (static-m softmax, prefetched) ----------------
// grid (16 q-tiles, 64 bh). 4 waves x 32 q-rows. KV tiles of 64.
// Swapped QK^T: St[key][q] = mfma(K_frag, Q_frag). Q is pre-scaled by log2e/8,
// so p = exp2(st) directly (no running max needed: |st| <~ 40, f32/bf16 safe,
// normalization at the end divides it out exactly).
__global__ __launch_bounds__(256, 3)
void attn_fwd(const bf16* __restrict__ Qp, const bf16* __restrict__ Kp,
              const bf16* __restrict__ Vt, const u32* __restrict__ mbits,
              bf16* __restrict__ X) {
  int lin = blockIdx.y * 16 + blockIdx.x;          // 1024 wgs
  int swz = (lin & 7) * 128 + (lin >> 3);          // XCD swizzle: 8 bh per XCD chunk
  int qt = swz & 15, bh = swz >> 4;
  int b = bh >> 4, h = bh & 15;
  int q0 = qt * 128;

  const int tid = threadIdx.x;
  const int lane = tid & 63, w = tid >> 6;
  const int c = lane & 15, g = lane >> 4;

  __shared__ char smem[32768];
  char* sK = smem;                  // [64 keys][64 d] bf16, 16B-block XOR swizzled
  char* sV = smem + 8192;           // [64 d][64 keys]
  char* sPw = smem + 16384 + w * 4096;   // per-wave P: [32 q][64 keys] bf16, swizzled

  // ---- hoisted swizzled LDS addresses (0 VALU in the hot loop) ----
  const int c7 = c & 7;
  const int y0 = (g ^ c7) << 4;           // kk=0 : block g
  const int y1 = ((4 + g) ^ c7) << 4;     // kk=1 : block 4+g
  const char* kaddr0 = sK + c * 128 + y0;
  const char* kaddr1 = sK + c * 128 + y1;
  const char* vaddr0 = sV + c * 128 + y0;
  const char* vaddr1 = sV + c * 128 + y1;
  const char* paddr0 = sPw + c * 128 + y0;
  const char* paddr1 = sPw + c * 128 + y1;
  char* pw[4];
#pragma unroll
  for (int nk = 0; nk < 4; ++nk)
    pw[nk] = sPw + c * 128 + ((g & 1) * 8) + (((nk * 2 + (g >> 1)) ^ c7) << 4);

  // ---- staging addresses (fixed per thread) ----
  const int u1 = 256 + tid;
  const int r0 = tid >> 3, bb0 = tid & 7, r1 = u1 >> 3, bb1 = u1 & 7;
  char* dK0 = sK + r0 * 128 + ((bb0 ^ (r0 & 7)) << 4);
  char* dK1 = sK + r1 * 128 + ((bb1 ^ (r1 & 7)) << 4);
  char* dV0 = sV + r0 * 128 + ((bb0 ^ (r0 & 7)) << 4);
  char* dV1 = sV + r1 * 128 + ((bb1 ^ (r1 & 7)) << 4);
  const bf16* gK0 = Kp + (size_t)bh * 131072 + r0 * 64 + bb0 * 8;
  const bf16* gK1 = Kp + (size_t)bh * 131072 + r1 * 64 + bb1 * 8;
  const bf16* gV0 = Vt + ((size_t)(b * 1024 + h * 64 + r0)) * 2048 + bb0 * 8;
  const bf16* gV1 = Vt + ((size_t)(b * 1024 + h * 64 + r1)) * 2048 + bb1 * 8;

  // Q fragments (pre-scaled by log2e/8 in the projection GEMM)
  const bf16* Qbase = Qp + ((size_t)bh * 2048) * 64;
  bf16x8 qf[2][2];
#pragma unroll
  for (int nq = 0; nq < 2; ++nq) {
    int qg = q0 + w * 32 + nq * 16 + c;
#pragma unroll
    for (int kk = 0; kk < 2; ++kk)
      qf[nq][kk] = *(const bf16x8*)&Qbase[(size_t)qg * 64 + kk * 32 + g * 8];
  }

  // mask rows (own q-rows of this lane's two MFMA column slots)
  const u64* Mrow0 = (const u64*)(mbits + ((size_t)b * 2048 + (q0 + w * 32 + c)) * 64);
  const u64* Mrow1 = (const u64*)(mbits + ((size_t)b * 2048 + (q0 + w * 32 + 16 + c)) * 64);

  f32x4 oacc[4][2] = {};                  // [md][nq] : O^T[d][q]
  float lrun0 = 0.f, lrun1 = 0.f;

  // prologue: stage tile 0 into registers
  uint4 kr0 = *(const uint4*)gK0, kr1 = *(const uint4*)gK1;
  uint4 vr0 = *(const uint4*)gV0, vr1 = *(const uint4*)gV1;
  u64 mw0 = Mrow0[0], mw1 = Mrow1[0];

  for (int t = 0; t < 32; ++t) {
    __syncthreads();                       // previous tile's LDS reads done
    *(uint4*)dK0 = kr0; *(uint4*)dK1 = kr1;
    *(uint4*)dV0 = vr0; *(uint4*)dV1 = vr1;
    __syncthreads();

    // prefetch next tile (global latency hides under this tile's compute)
    u64 mn0 = 0, mn1 = 0;
    if (t < 31) {
      kr0 = *(const uint4*)(gK0 + (size_t)(t + 1) * 4096);
      kr1 = *(const uint4*)(gK1 + (size_t)(t + 1) * 4096);
      vr0 = *(const uint4*)(gV0 + (size_t)(t + 1) * 64);
      vr1 = *(const uint4*)(gV1 + (size_t)(t + 1) * 64);
      mn0 = Mrow0[t + 1];
      mn1 = Mrow1[t + 1];
    }

    // QK^T (swapped): St[key][q]
    f32x4 st[4][2] = {};
#pragma unroll
    for (int nk = 0; nk < 4; ++nk) {
      bf16x8 kfa = *(const bf16x8*)(kaddr0 + nk * 2048);
      st[nk][0] = __builtin_amdgcn_mfma_f32_16x16x32_bf16(kfa, qf[0][0], st[nk][0], 0, 0, 0);
      st[nk][1] = __builtin_amdgcn_mfma_f32_16x16x32_bf16(kfa, qf[1][0], st[nk][1], 0, 0, 0);
      bf16x8 kfb = *(const bf16x8*)(kaddr1 + nk * 2048);
      st[nk][0] = __builtin_amdgcn_mfma_f32_16x16x32_bf16(kfb, qf[0][1], st[nk][0], 0, 0, 0);
      st[nk][1] = __builtin_amdgcn_mfma_f32_16x16x32_bf16(kfb, qf[1][1], st[nk][1], 0, 0, 0);
    }

    // static-m softmax: p = mask ? exp2(st) : 0 ; pack to bf16 pairs -> LDS
#pragma unroll
    for (int nq = 0; nq < 2; ++nq) {
      u64 ms = (nq ? mw1 : mw0) >> (4 * g);   // bit (16*nk + r) is key nk*16+g*4+r
      u32 ma = (u32)ms;                        // nk 0 (bits 0-3), nk 1 (bits 16-19)
      u32 mb = (u32)(ms >> 32);                // nk 2,3
      float ls = 0.f;
#pragma unroll
      for (int nk = 0; nk < 4; ++nk) {
        u32 msel = (nk < 2) ? ma : mb;
        const int bs = (nk & 1) * 16;
#pragma unroll
        for (int tt = 0; tt < 2; ++tt) {
          float e0 = __builtin_amdgcn_exp2f(st[nk][nq][tt * 2]);
          float e1 = __builtin_amdgcn_exp2f(st[nk][nq][tt * 2 + 1]);
          e0 = (msel & (1u << (bs + tt * 2)))     ? e0 : 0.f;
          e1 = (msel & (1u << (bs + tt * 2 + 1))) ? e1 : 0.f;
          ls += e0;
          ls += e1;
          union { bf16 h2[2]; u32 uu; } pk;
          pk.h2[0] = (bf16)e0; pk.h2[1] = (bf16)e1;
          *(u32*)(pw[nk] + nq * 2048 + tt * 4) = pk.uu;
        }
      }
      if (nq) lrun1 += ls; else lrun0 += ls;
    }

    // PV: O^T[d][q] += Vt . P^T
#pragma unroll
    for (int kk = 0; kk < 2; ++kk) {
      const char* pa = kk ? paddr1 : paddr0;
      const char* va = kk ? vaddr1 : vaddr0;
      bf16x8 pf0 = *(const bf16x8*)(pa);
      bf16x8 pf1 = *(const bf16x8*)(pa + 2048);
#pragma unroll
      for (int md = 0; md < 4; ++md) {
        bf16x8 vf = *(const bf16x8*)(va + md * 2048);
        oacc[md][0] = __builtin_amdgcn_mfma_f32_16x16x32_bf16(vf, pf0, oacc[md][0], 0, 0, 0);
        oacc[md][1] = __builtin_amdgcn_mfma_f32_16x16x32_bf16(vf, pf1, oacc[md][1], 0, 0, 0);
      }
    }

    mw0 = mn0; mw1 = mn1;
  }

  // final softmax denominators (one cross-lane reduce per block)
  lrun0 += __shfl_xor(lrun0, 16); lrun0 += __shfl_xor(lrun0, 32);
  lrun1 += __shfl_xor(lrun1, 16); lrun1 += __shfl_xor(lrun1, 32);
  float inv0 = 1.f / lrun0;
  float inv1 = 1.f / lrun1;

  // epilogue: O^T -> LDS transpose -> coalesced bf16 write to X[b*2048+q][h*64+d]
  __syncthreads();
  char* Xl = smem;                         // 16KB: [128 q][64 d] bf16, swizzled
#pragma unroll
  for (int nq = 0; nq < 2; ++nq) {
    float inv = nq ? inv1 : inv0;
    int ql = w * 32 + nq * 16 + c;         // block-local q row
#pragma unroll
    for (int md = 0; md < 4; ++md)
#pragma unroll
      for (int r = 0; r < 4; ++r) {
        int d = md * 16 + g * 4 + r;
        int blk = d >> 3, off = d & 7;
        *(bf16*)(Xl + ql * 128 + ((blk ^ (ql & 7)) << 4) + off * 2) =
            (bf16)(oacc[md][nq][r] * inv);
      }
  }
  __syncthreads();
#pragma unroll
  for (int i = 0; i < 4; ++i) {
    int u = i * 256 + tid;                 // 0..1023 : row=u>>3, blk=u&7
    int row = u >> 3, blk = u & 7;
    uint4 xv = *(const uint4*)(Xl + row * 128 + ((blk ^ (row & 7)) << 4));
    *(uint4*)&X[(size_t)(b * 2048 + q0 + row) * 1024 + h * 64 + blk * 8] = xv;
  }
}

// ---------------- launch ----------------

extern "C" void kernel_launch(void* const* d_in, const int* in_sizes, int n_in,
                              void* d_out, int out_size, void* d_ws, size_t ws_size,
                              hipStream_t stream) {
  const float* q    = (const float*)d_in[0];
  const float* k    = (const float*)d_in[1];
  const float* v    = (const float*)d_in[2];
  const int*   mask = (const int*)d_in[3];
  const float* Wq   = (const float*)d_in[4];
  const float* Wk   = (const float*)d_in[5];
  const float* Wv   = (const float*)d_in[6];
  const float* Wo   = (const float*)d_in[7];
  const float* Wb   = (const float*)d_in[8];

  char* ws = (char*)d_ws;
  bf16* qb = (bf16*)(ws + 0);             // 16 MB each
  bf16* kb = (bf16*)(ws + 16777216);
  bf16* vb = (bf16*)(ws + 33554432);
  bf16* Wt = (bf16*)(ws + 50331648);      // 8 MB (4 packed 1024x1024)
  bf16* Qp = (bf16*)(ws + 58720256);
  bf16* Kp = (bf16*)(ws + 75497472);
  bf16* Vt = (bf16*)(ws + 92274688);
  bf16* Xb = (bf16*)(ws + 109051904);
  u32*  mb = (u32*) (ws + 125829120);     // 2 MB bitmask

  cvt_f32_bf16<<<1024, 256, 0, stream>>>(q, qb, 1048576);
  cvt_f32_bf16<<<1024, 256, 0, stream>>>(k, kb, 1048576);
  cvt_f32_bf16<<<1024, 256, 0, stream>>>(v, vb, 1048576);
  pack_w<<<dim3(512, 1, 4), 256, 0, stream>>>(Wq, Wk, Wv, Wo, Wt);
  pack_mask<<<2048, 256, 0, stream>>>(mask, mb, 16777216);

  // Q = (q.Wq) * log2e/8, K = k.Wk  -> [bh][l][d]
  gemm_bt<0><<<dim3(8, 64, 1), 256, 0, stream>>>(qb, Wt,            Qp, nullptr, 0, 0, SCALE_L2E);
  gemm_bt<0><<<dim3(8, 64, 1), 256, 0, stream>>>(kb, Wt + 1048576,  Kp, nullptr, 0, 0, 1.0f);
  // Vt[b][hd][l] = Wv^T . v^T  per batch
  gemm_bt<1><<<dim3(16, 8, 4), 256, 0, stream>>>(Wt + 2097152, vb,  Vt, nullptr, 0, 2097152, 1.0f);

  attn_fwd<<<dim3(16, 64, 1), 256, 0, stream>>>(Qp, Kp, Vt, mb, Xb);

  // out = X . Wo^T + b  (f32 out)
  gemm_bt<2><<<dim3(8, 64, 1), 256, 0, stream>>>(Xb, Wt + 3145728, (float*)d_out, Wb, 0, 0, 1.0f);
}

// Round 3
// 263.930 us; speedup vs baseline: 1.4940x; 1.0957x over previous
//
#include <hip/hip_runtime.h>
#include <stdint.h>

typedef __bf16 bf16;
typedef __bf16 bf16x8 __attribute__((ext_vector_type(8)));
typedef float  f32x4  __attribute__((ext_vector_type(4)));
typedef uint32_t u32;
typedef uint64_t u64;

#define SCALE_L2E 0.18033688011112042f   // (1/8) * log2(e)

__device__ __forceinline__ void gld_lds16(const void* gsrc, void* ldst) {
  __builtin_amdgcn_global_load_lds(
      (const __attribute__((address_space(1))) void*)gsrc,
      (__attribute__((address_space(3))) void*)ldst, 16, 0, 0);
}

// ---------------- stage 1: conversions / packing ----------------

// q,k,v f32 -> bf16, one dispatch (z selects input)
__global__ void cvt3(const float* __restrict__ q, const float* __restrict__ k,
                     const float* __restrict__ v, bf16* __restrict__ out) {
  const float* in = (blockIdx.z == 0) ? q : (blockIdx.z == 1) ? k : v;
  bf16* o = out + (size_t)blockIdx.z * 8388608;
  int stride = gridDim.x * blockDim.x;
  for (int i = blockIdx.x * blockDim.x + threadIdx.x; i < 1048576; i += stride) {
    const float4* p = (const float4*)(in + (size_t)i * 8);
    float4 a = p[0], b = p[1];
    bf16x8 vv;
    vv[0]=(bf16)a.x; vv[1]=(bf16)a.y; vv[2]=(bf16)a.z; vv[3]=(bf16)a.w;
    vv[4]=(bf16)b.x; vv[5]=(bf16)b.y; vv[6]=(bf16)b.z; vv[7]=(bf16)b.w;
    *(bf16x8*)(o + (size_t)i * 8) = vv;
  }
}

// Wt layout: 4 matrices [1024][1024], row n contiguous over k.
// s<3: Wt[s][n][k] = Ws[h=n>>6][m=k][d=n&63];  s==3: Wt[3][n][k] = Wo[n][k]
__global__ void pack_w(const float* __restrict__ Wq, const float* __restrict__ Wk,
                       const float* __restrict__ Wv, const float* __restrict__ Wo,
                       bf16* __restrict__ Wt) {
  int s = blockIdx.z;
  int tid = blockIdx.x * blockDim.x + threadIdx.x;   // 0..131071
  int n = tid >> 7, kb = tid & 127;
  const float* W = (s == 0) ? Wq : (s == 1) ? Wk : (s == 2) ? Wv : Wo;
  bf16x8 v;
  if (s < 3) {
#pragma unroll
    for (int j = 0; j < 8; ++j)
      v[j] = (bf16)W[((n >> 6) << 16) + (kb * 8 + j) * 64 + (n & 63)];
  } else {
    const float4* p = (const float4*)&W[n * 1024 + kb * 8];
    float4 a = p[0], b = p[1];
    v[0]=(bf16)a.x; v[1]=(bf16)a.y; v[2]=(bf16)a.z; v[3]=(bf16)a.w;
    v[4]=(bf16)b.x; v[5]=(bf16)b.y; v[6]=(bf16)b.z; v[7]=(bf16)b.w;
  }
  *(bf16x8*)&Wt[(size_t)s * 1048576 + (size_t)n * 1024 + kb * 8] = v;
}

// mask int32 -> bitmask, bit (b,l,key) at mbits[(b*2048+l)*64 + key/32], bit key&31
__global__ void pack_mask(const int* __restrict__ mask, u32* __restrict__ mbits, int total) {
  int stride = gridDim.x * blockDim.x;
  for (int idx = blockIdx.x * blockDim.x + threadIdx.x; idx < total; idx += stride) {
    int v = mask[idx];
    u64 bal = __ballot(v != 0);
    if ((threadIdx.x & 63) == 0)
      *(u64*)&mbits[idx >> 5] = bal;
  }
}

// ---------------- stage 2: bf16 GEMM, 2-phase double-buffered (T3 minimum) ----------------
// C = A(row,k) . Bt(col,k)^T, K=1024. Tiles 128x128, BK=32, 4 waves.
// EPI 0: fused Q|K projection. rows<8192 -> Q (Bt=Wq-pack, scale, Cout);
//        rows>=8192 -> K (Bt+=1M, scale=1, Cout2). bf16 [bh][l][d].
// EPI 1: write bf16 at [(bz*1024+row)*2048+col] (Vt)
// EPI 2: write f32 d_out[row*1024+col] + bias[col]
template<int EPI>
__global__ __launch_bounds__(256, 2)
void gemm_bt(const bf16* __restrict__ A, const bf16* __restrict__ Bt,
             void* __restrict__ Cout, void* __restrict__ Cout2,
             const float* __restrict__ bias,
             size_t a_bstride, size_t b_bstride, float cscale) {
  const int gx = gridDim.x;
  int lin = blockIdx.y * gx + blockIdx.x;
  int nwg = gx * gridDim.y;
  int swz = (lin & 7) * (nwg >> 3) + (lin >> 3);   // XCD-contiguous chunks (nwg % 8 == 0)
  int bx = swz % gx, by = swz / gx;
  const int bz = blockIdx.z;
  A  += a_bstride * bz;
  Bt += b_bstride * bz;
  const int row0 = by * 128, col0 = bx * 128;
  bool isK = false;
  if (EPI == 0 && row0 >= 8192) { isK = true; Bt += 1048576; }

  __shared__ bf16 sA[2][4096];
  __shared__ bf16 sB[2][4096];

  const int lane = threadIdx.x & 63, w = threadIdx.x >> 6;
  const int c = lane & 15, g = lane >> 4;
  const int wr = w >> 1, wc = w & 1;

  // staging source coords (fixed per thread)
  const int u0 = w * 128 + lane;
  const int rs0 = u0 >> 2, ps0 = u0 & 3;
  const int rs1 = (u0 + 64) >> 2, ps1 = (u0 + 64) & 3;
  const bf16* Ap = A + (size_t)row0 * 1024;
  const bf16* Bp = Bt + (size_t)col0 * 1024;
  const bf16* As0 = Ap + (size_t)rs0 * 1024 + ps0 * 8;
  const bf16* As1 = Ap + (size_t)rs1 * 1024 + ps1 * 8;
  const bf16* Bs0 = Bp + (size_t)rs0 * 1024 + ps0 * 8;
  const bf16* Bs1 = Bp + (size_t)rs1 * 1024 + ps1 * 8;

  f32x4 acc[4][4] = {};

  // prologue: stage k-tile 0 into buf 0
  gld_lds16(As0, (char*)&sA[0][0] + (w * 2) * 1024);
  gld_lds16(As1, (char*)&sA[0][0] + (w * 2 + 1) * 1024);
  gld_lds16(Bs0, (char*)&sB[0][0] + (w * 2) * 1024);
  gld_lds16(Bs1, (char*)&sB[0][0] + (w * 2 + 1) * 1024);

  for (int k0 = 0; k0 < 1024; k0 += 32) {
    __syncthreads();                       // drains my stage(k0) (issued a full tile ago)
    int cb = (k0 >> 5) & 1, nb = cb ^ 1;
    if (k0 < 992) {                        // stage k0+32 into buf^1 (hides under MFMA)
      gld_lds16(As0 + k0 + 32, (char*)&sA[nb][0] + (w * 2) * 1024);
      gld_lds16(As1 + k0 + 32, (char*)&sA[nb][0] + (w * 2 + 1) * 1024);
      gld_lds16(Bs0 + k0 + 32, (char*)&sB[nb][0] + (w * 2) * 1024);
      gld_lds16(Bs1 + k0 + 32, (char*)&sB[nb][0] + (w * 2 + 1) * 1024);
    }

    bf16x8 af[4], bfr[4];
#pragma unroll
    for (int m = 0; m < 4; ++m)
      af[m] = *(const bf16x8*)&sA[cb][(wr * 64 + m * 16 + c) * 32 + g * 8];
#pragma unroll
    for (int n = 0; n < 4; ++n)
      bfr[n] = *(const bf16x8*)&sB[cb][(wc * 64 + n * 16 + c) * 32 + g * 8];
#pragma unroll
    for (int m = 0; m < 4; ++m)
#pragma unroll
      for (int n = 0; n < 4; ++n)
        acc[m][n] = __builtin_amdgcn_mfma_f32_16x16x32_bf16(af[m], bfr[n], acc[m][n], 0, 0, 0);
  }

  float csc = (EPI == 0 && isK) ? 1.0f : cscale;
#pragma unroll
  for (int m = 0; m < 4; ++m) {
    int row_base = row0 + wr * 64 + m * 16 + g * 4;
#pragma unroll
    for (int n = 0; n < 4; ++n) {
      int col = col0 + wc * 64 + n * 16 + c;
#pragma unroll
      for (int r = 0; r < 4; ++r) {
        int row = row_base + r;
        float val = acc[m][n][r];
        if (EPI == 0) {
          int rl = row & 8191;
          int b = rl >> 11, l = rl & 2047, h = col >> 6, d = col & 63;
          bf16* dst = isK ? (bf16*)Cout2 : (bf16*)Cout;
          dst[(((size_t)(b * 16 + h) * 2048 + l) << 6) + d] = (bf16)(val * csc);
        } else if (EPI == 1) {
          ((bf16*)Cout)[((size_t)(bz * 1024 + row)) * 2048 + col] = (bf16)val;
        } else {
          ((float*)Cout)[(size_t)row * 1024 + col] = val + bias[col];
        }
      }
    }
  }
}

// ---------------- stage 3: flash attention (static-m softmax, dbuf, 1 barrier/tile) ----------------
__global__ __launch_bounds__(256, 3)
void attn_fwd(const bf16* __restrict__ Qp, const bf16* __restrict__ Kp,
              const bf16* __restrict__ Vt, const u32* __restrict__ mbits,
              bf16* __restrict__ X) {
  int lin = blockIdx.y * 16 + blockIdx.x;          // 1024 wgs
  int swz = (lin & 7) * 128 + (lin >> 3);          // XCD swizzle: 8 bh per XCD chunk
  int qt = swz & 15, bh = swz >> 4;
  int b = bh >> 4, h = bh & 15;
  int q0 = qt * 128;

  const int tid = threadIdx.x;
  const int lane = tid & 63, w = tid >> 6;
  const int c = lane & 15, g = lane >> 4;

  __shared__ char smem[49152];
  // [2] x { K [64 keys][64 d] 8KB | V [64 d][64 keys] 8KB }, 16B-block XOR swizzled
  char* sKV = smem;
  char* sPw = smem + 32768 + w * 4096;   // per-wave P: [32 q][64 keys] bf16, swizzled

  // ---- hoisted swizzled LDS offsets ----
  const int c7 = c & 7;
  const int y0 = (g ^ c7) << 4;           // kk=0 : block g
  const int y1 = ((4 + g) ^ c7) << 4;     // kk=1 : block 4+g
  const int ko0 = c * 128 + y0;           // K read, rel. to buf base
  const int ko1 = c * 128 + y1;
  const int vo0 = 8192 + c * 128 + y0;    // V read
  const int vo1 = 8192 + c * 128 + y1;
  const char* paddr0 = sPw + c * 128 + y0;
  const char* paddr1 = sPw + c * 128 + y1;
  char* pw[4];
#pragma unroll
  for (int nk = 0; nk < 4; ++nk)
    pw[nk] = sPw + c * 128 + ((g & 1) * 8) + (((nk * 2 + (g >> 1)) ^ c7) << 4);

  // ---- staging coords (fixed per thread) ----
  const int r0 = tid >> 3, bb0 = tid & 7;
  const int r1 = (256 + tid) >> 3, bb1 = tid & 7;
  const int dK0 = r0 * 128 + ((bb0 ^ (r0 & 7)) << 4);
  const int dK1 = r1 * 128 + ((bb1 ^ (r1 & 7)) << 4);
  const int dV0 = 8192 + dK0;
  const int dV1 = 8192 + dK1;
  const bf16* gK0 = Kp + (size_t)bh * 131072 + r0 * 64 + bb0 * 8;
  const bf16* gK1 = Kp + (size_t)bh * 131072 + r1 * 64 + bb1 * 8;
  const bf16* gV0 = Vt + ((size_t)(b * 1024 + h * 64 + r0)) * 2048 + bb0 * 8;
  const bf16* gV1 = Vt + ((size_t)(b * 1024 + h * 64 + r1)) * 2048 + bb1 * 8;

  // Q fragments (pre-scaled by log2e/8 in the projection GEMM)
  const bf16* Qbase = Qp + ((size_t)bh * 2048) * 64;
  bf16x8 qf[2][2];
#pragma unroll
  for (int nq = 0; nq < 2; ++nq) {
    int qg = q0 + w * 32 + nq * 16 + c;
#pragma unroll
    for (int kk = 0; kk < 2; ++kk)
      qf[nq][kk] = *(const bf16x8*)&Qbase[(size_t)qg * 64 + kk * 32 + g * 8];
  }

  const u64* Mrow0 = (const u64*)(mbits + ((size_t)b * 2048 + (q0 + w * 32 + c)) * 64);
  const u64* Mrow1 = (const u64*)(mbits + ((size_t)b * 2048 + (q0 + w * 32 + 16 + c)) * 64);

  f32x4 oacc[4][2] = {};                  // [md][nq] : O^T[d][q]
  float lrun0 = 0.f, lrun1 = 0.f;

  // prologue: tile 0 -> regs -> LDS buf 0
  {
    uint4 kr0 = *(const uint4*)gK0, kr1 = *(const uint4*)gK1;
    uint4 vr0 = *(const uint4*)gV0, vr1 = *(const uint4*)gV1;
    *(uint4*)(sKV + dK0) = kr0; *(uint4*)(sKV + dK1) = kr1;
    *(uint4*)(sKV + dV0) = vr0; *(uint4*)(sKV + dV1) = vr1;
  }
  u64 mw0 = Mrow0[0], mw1 = Mrow1[0];

  for (int t = 0; t < 32; ++t) {
    __syncthreads();                       // buf[t&1] staged & visible; prev reads done
    const char* kbuf = sKV + ((t & 1) << 14);

    // issue next-tile global loads (land during this tile's compute)
    uint4 kr0, kr1, vr0, vr1;
    u64 mn0 = 0, mn1 = 0;
    if (t < 31) {
      kr0 = *(const uint4*)(gK0 + (size_t)(t + 1) * 4096);
      kr1 = *(const uint4*)(gK1 + (size_t)(t + 1) * 4096);
      vr0 = *(const uint4*)(gV0 + (size_t)(t + 1) * 64);
      vr1 = *(const uint4*)(gV1 + (size_t)(t + 1) * 64);
      mn0 = Mrow0[t + 1];
      mn1 = Mrow1[t + 1];
    }

    // QK^T (swapped): St[key][q]
    f32x4 st[4][2] = {};
#pragma unroll
    for (int nk = 0; nk < 4; ++nk) {
      bf16x8 kfa = *(const bf16x8*)(kbuf + ko0 + nk * 2048);
      st[nk][0] = __builtin_amdgcn_mfma_f32_16x16x32_bf16(kfa, qf[0][0], st[nk][0], 0, 0, 0);
      st[nk][1] = __builtin_amdgcn_mfma_f32_16x16x32_bf16(kfa, qf[1][0], st[nk][1], 0, 0, 0);
      bf16x8 kfb = *(const bf16x8*)(kbuf + ko1 + nk * 2048);
      st[nk][0] = __builtin_amdgcn_mfma_f32_16x16x32_bf16(kfb, qf[0][1], st[nk][0], 0, 0, 0);
      st[nk][1] = __builtin_amdgcn_mfma_f32_16x16x32_bf16(kfb, qf[1][1], st[nk][1], 0, 0, 0);
    }

    // static-m softmax: p = mask ? exp2(st) : 0 ; pack bf16 pairs -> LDS
#pragma unroll
    for (int nq = 0; nq < 2; ++nq) {
      u64 ms = (nq ? mw1 : mw0) >> (4 * g);   // bit (16*nk + r) is key nk*16+g*4+r
      u32 ma = (u32)ms;
      u32 mb = (u32)(ms >> 32);
      float ls = 0.f;
#pragma unroll
      for (int nk = 0; nk < 4; ++nk) {
        u32 msel = (nk < 2) ? ma : mb;
        const int bs = (nk & 1) * 16;
#pragma unroll
        for (int tt = 0; tt < 2; ++tt) {
          float e0 = __builtin_amdgcn_exp2f(st[nk][nq][tt * 2]);
          float e1 = __builtin_amdgcn_exp2f(st[nk][nq][tt * 2 + 1]);
          e0 = (msel & (1u << (bs + tt * 2)))     ? e0 : 0.f;
          e1 = (msel & (1u << (bs + tt * 2 + 1))) ? e1 : 0.f;
          ls += e0;
          ls += e1;
          union { bf16 h2[2]; u32 uu; } pk;
          pk.h2[0] = (bf16)e0; pk.h2[1] = (bf16)e1;
          *(u32*)(pw[nk] + nq * 2048 + tt * 4) = pk.uu;
        }
      }
      if (nq) lrun1 += ls; else lrun0 += ls;
    }

    // PV: O^T[d][q] += Vt . P^T
#pragma unroll
    for (int kk = 0; kk < 2; ++kk) {
      const char* pa = kk ? paddr1 : paddr0;
      const int vo = kk ? vo1 : vo0;
      bf16x8 pf0 = *(const bf16x8*)(pa);
      bf16x8 pf1 = *(const bf16x8*)(pa + 2048);
#pragma unroll
      for (int md = 0; md < 4; ++md) {
        bf16x8 vf = *(const bf16x8*)(kbuf + vo + md * 2048);
        oacc[md][0] = __builtin_amdgcn_mfma_f32_16x16x32_bf16(vf, pf0, oacc[md][0], 0, 0, 0);
        oacc[md][1] = __builtin_amdgcn_mfma_f32_16x16x32_bf16(vf, pf1, oacc[md][1], 0, 0, 0);
      }
    }

    // write next tile into buf^1 (loads have had the whole compute to land)
    if (t < 31) {
      char* nbuf = sKV + (((t + 1) & 1) << 14);
      *(uint4*)(nbuf + dK0) = kr0; *(uint4*)(nbuf + dK1) = kr1;
      *(uint4*)(nbuf + dV0) = vr0; *(uint4*)(nbuf + dV1) = vr1;
    }
    mw0 = mn0; mw1 = mn1;
  }

  // final softmax denominators
  lrun0 += __shfl_xor(lrun0, 16); lrun0 += __shfl_xor(lrun0, 32);
  lrun1 += __shfl_xor(lrun1, 16); lrun1 += __shfl_xor(lrun1, 32);
  float inv0 = 1.f / lrun0;
  float inv1 = 1.f / lrun1;

  // epilogue: O^T -> LDS transpose -> coalesced bf16 write to X[b*2048+q][h*64+d]
  __syncthreads();
  char* Xl = smem;                         // 16KB: [128 q][64 d] bf16, swizzled
#pragma unroll
  for (int nq = 0; nq < 2; ++nq) {
    float inv = nq ? inv1 : inv0;
    int ql = w * 32 + nq * 16 + c;
#pragma unroll
    for (int md = 0; md < 4; ++md)
#pragma unroll
      for (int r = 0; r < 4; ++r) {
        int d = md * 16 + g * 4 + r;
        int blk = d >> 3, off = d & 7;
        *(bf16*)(Xl + ql * 128 + ((blk ^ (ql & 7)) << 4) + off * 2) =
            (bf16)(oacc[md][nq][r] * inv);
      }
  }
  __syncthreads();
#pragma unroll
  for (int i = 0; i < 4; ++i) {
    int u = i * 256 + tid;
    int row = u >> 3, blk = u & 7;
    uint4 xv = *(const uint4*)(Xl + row * 128 + ((blk ^ (row & 7)) << 4));
    *(uint4*)&X[(size_t)(b * 2048 + q0 + row) * 1024 + h * 64 + blk * 8] = xv;
  }
}

// ---------------- launch ----------------

extern "C" void kernel_launch(void* const* d_in, const int* in_sizes, int n_in,
                              void* d_out, int out_size, void* d_ws, size_t ws_size,
                              hipStream_t stream) {
  const float* q    = (const float*)d_in[0];
  const float* k    = (const float*)d_in[1];
  const float* v    = (const float*)d_in[2];
  const int*   mask = (const int*)d_in[3];
  const float* Wq   = (const float*)d_in[4];
  const float* Wk   = (const float*)d_in[5];
  const float* Wv   = (const float*)d_in[6];
  const float* Wo   = (const float*)d_in[7];
  const float* Wb   = (const float*)d_in[8];

  char* ws = (char*)d_ws;
  bf16* qb = (bf16*)(ws + 0);             // 16 MB each; qb|kb|vb contiguous
  bf16* kb = (bf16*)(ws + 16777216);
  bf16* vb = (bf16*)(ws + 33554432);
  bf16* Wt = (bf16*)(ws + 50331648);      // 8 MB (4 packed 1024x1024)
  bf16* Qp = (bf16*)(ws + 58720256);
  bf16* Kp = (bf16*)(ws + 75497472);
  bf16* Vt = (bf16*)(ws + 92274688);
  bf16* Xb = (bf16*)(ws + 109051904);
  u32*  mb = (u32*) (ws + 125829120);     // 2 MB bitmask

  cvt3<<<dim3(512, 1, 3), 256, 0, stream>>>(q, k, v, qb);
  pack_w<<<dim3(512, 1, 4), 256, 0, stream>>>(Wq, Wk, Wv, Wo, Wt);
  pack_mask<<<2048, 256, 0, stream>>>(mask, mb, 16777216);

  // fused: Q = (q.Wq)*log2e/8 and K = k.Wk  -> [bh][l][d]
  gemm_bt<0><<<dim3(8, 128, 1), 256, 0, stream>>>(qb, Wt, Qp, Kp, nullptr, 0, 0, SCALE_L2E);
  // Vt[b][hd][l] = Wv^T . v^T  per batch
  gemm_bt<1><<<dim3(16, 8, 4), 256, 0, stream>>>(Wt + 2097152, vb, Vt, nullptr, nullptr, 0, 2097152, 1.0f);

  attn_fwd<<<dim3(16, 64, 1), 256, 0, stream>>>(Qp, Kp, Vt, mb, Xb);

  // out = X . Wo^T + b  (f32 out)
  gemm_bt<2><<<dim3(8, 64, 1), 256, 0, stream>>>(Xb, Wt + 3145728, (float*)d_out, nullptr, Wb, 0, 0, 1.0f);
}